// Round 7
// baseline (382.914 us; speedup 1.0000x reference)
//
#include <hip/hip_runtime.h>
#include <math.h>

// Problem constants
#define BB 8
#define KK 4
#define LL 1024
#define DD 512
#define HD 64
#define D3 1536
#define MM (BB*LL*KK)   // 32768 rows for per-state GEMMs
#define BL (BB*LL)      // 8192 (b,l) positions
#define SCALE 0.125f
#define EPSF 1e-8f
#define LN_EPSF 1e-5f

typedef _Float16 hfrag __attribute__((ext_vector_type(8)));
typedef float f32x4 __attribute__((ext_vector_type(4)));

__device__ __forceinline__ unsigned short f2h(float f) {
    _Float16 h = (_Float16)f;
    unsigned short u; __builtin_memcpy(&u, &h, 2); return u;
}
__device__ __forceinline__ float h2f(unsigned short u) {
    _Float16 h; __builtin_memcpy(&h, &u, 2); return (float)h;
}

__device__ __forceinline__ void glds16(const unsigned short* g, unsigned short* l) {
    __builtin_amdgcn_global_load_lds(
        (const __attribute__((address_space(1))) void*)g,
        (__attribute__((address_space(3))) void*)l, 16, 0, 0);
}

// Inline nsw: normalized state weight for (b,k) from sw/pres (32 elems, L2-hot)
__device__ __forceinline__ void nsw_compute(const float* sw, const int* pres,
                                            int b, float* nswv) {
    float w[KK], pr[KK]; float denom = 0.f, ps = 0.f;
    #pragma unroll
    for (int k = 0; k < KK; ++k) {
        pr[k] = pres[b*KK + k] ? 1.f : 0.f;
        w[k]  = sw[b*KK + k] * pr[k];
        denom += w[k]; ps += pr[k];
    }
    #pragma unroll
    for (int k = 0; k < KK; ++k)
        nswv[k] = (denom > EPSF) ? w[k] / fmaxf(denom, EPSF)
                                 : pr[k] / fmaxf(ps, 1.f);
}

// ---------------------------------------------------------------------------
// Fused fp32 -> fp16 weight conversion.
// Wqkv region [0, 3*WSZ) is written FRAGMENT-MAJOR: element (n,k) of the
// fused (1536,512) weight goes to ((nb*16+kt)*64 + q*16 + fr)*8 + e, with
// nb=n>>4, fr=n&15, kt=k>>5, q=(k>>3)&3, e=k&7 — so a wave's MFMA B-fragment
// load is one contiguous 1KB global_load_dwordx4 (round-4's uncoalesced
// failure fixed at the producer).  Wo|Wg1|Wg2 stay row-major.
#define WSZ 262144          // 512*512
#define OG1 1048576         // start of Wg1 (512*1536)
#define OG2 1835008         // start of Wg2
#define WTOT 2097152
__global__ __launch_bounds__(256) void cvt_weights(
        const float* __restrict__ Wq, const float* __restrict__ Wk,
        const float* __restrict__ Wv, const float* __restrict__ Wo,
        const float* __restrict__ Wg1, const float* __restrict__ Wg2,
        unsigned short* __restrict__ dst) {
    int t = blockIdx.x * 256 + threadIdx.x;   // one float4 per thread
    int e = t * 4;
    if (e < 3*WSZ) {
        const float* src; int off;
        if      (e < WSZ)   { src = Wq; off = e; }
        else if (e < 2*WSZ) { src = Wk; off = e - WSZ; }
        else                { src = Wv; off = e - 2*WSZ; }
        float4 v = *(const float4*)(src + off);
        ushort4 o;
        o.x = f2h(v.x); o.y = f2h(v.y); o.z = f2h(v.z); o.w = f2h(v.w);
        const int n = e >> 9;          // global row in fused 1536
        const int k = e & 511;
        const int nb = n >> 4, fr = n & 15;
        const int kt = k >> 5, q = (k >> 3) & 3, e0 = k & 7;
        const size_t di = ((size_t)(nb*16 + kt)*64 + q*16 + fr)*8 + e0;
        *(ushort4*)(dst + di) = o;
        return;
    }
    const float* src; int off;
    if      (e < OG1) { src = Wo;  off = e - 3*WSZ; }
    else if (e < OG2) { src = Wg1; off = e - OG1; }
    else              { src = Wg2; off = e - OG2; }
    float4 v = *(const float4*)(src + off);
    ushort4 o;
    o.x = f2h(v.x); o.y = f2h(v.y); o.z = f2h(v.z); o.w = f2h(v.w);
    *(ushort4*)(dst + e) = o;
}

// ---------------------------------------------------------------------------
// Build x (fp16, FRAGMENT-MAJOR for the QKV GEMM) + weighted_mean/max_feat
// (fp32, exact) + rowmask + f_nsw.  X element (m = bl*4+k, d) goes to
// ((mb*16+kt)*64 + q*16 + fr)*8 + e (mb=m>>4, fr=m&15, kt=d>>5, q=(d>>3)&3).
// X writes become 8B-scattered within 4KB regions (L2 absorbs); wm/mx writes
// stay coalesced.
__global__ __launch_bounds__(256) void buildx_kernel(
        const float* __restrict__ SR, const int* __restrict__ residue,
        const int* __restrict__ pres, const int* __restrict__ roles,
        const float* __restrict__ role_emb, const float* __restrict__ sw,
        unsigned short* __restrict__ Xh, float* __restrict__ rowmask,
        float* __restrict__ out_wm, float* __restrict__ out_mx,
        float* __restrict__ f_nsw) {
    int t  = blockIdx.x * 256 + threadIdx.x;
    int bl = t >> 7;
    int d4 = (t & 127) << 2;
    int b  = bl >> 10, l = bl & 1023;
    float nswv[KK];
    nsw_compute(sw, pres, b, nswv);
    float mk[KK], swr[KK];
    float ssum = 0.f, many = 0.f;
    #pragma unroll
    for (int k = 0; k < KK; ++k) {
        int bk = b*KK + k;
        bool valid = (residue[(size_t)bk*LL + l] != 0) && (pres[bk] != 0);
        mk[k]  = valid ? 1.f : 0.f;
        swr[k] = nswv[k] * mk[k];
        ssum += swr[k]; many += mk[k];
    }
    float inv = 1.f / fmaxf(ssum, EPSF);
    bool hasany = many > 0.5f;
    const int kt = d4 >> 5, fq = (d4 >> 3) & 3, e0 = d4 & 7;
    float wmx = 0.f, wmy = 0.f, wmz = 0.f, wmw = 0.f;
    float mxx = -1e9f, mxy = -1e9f, mxz = -1e9f, mxw = -1e9f;
    #pragma unroll
    for (int k = 0; k < KK; ++k) {
        int bk = b*KK + k;
        int role = roles[bk]; if (role < 0) role = 0;
        float4 sr = *(const float4*)(SR + ((size_t)bk*LL + l)*DD + d4);
        float4 re = *(const float4*)(role_emb + (size_t)role*DD + d4);
        float xx = (sr.x + re.x)*mk[k], xy = (sr.y + re.y)*mk[k];
        float xz = (sr.z + re.z)*mk[k], xw = (sr.w + re.w)*mk[k];
        ushort4 xs; xs.x = f2h(xx); xs.y = f2h(xy); xs.z = f2h(xz); xs.w = f2h(xw);
        const int m = bl*KK + k;
        const int mb = m >> 4, fr = m & 15;
        const size_t di = ((size_t)(mb*16 + kt)*64 + fq*16 + fr)*8 + e0;
        *(ushort4*)(Xh + di) = xs;
        float s = swr[k]*inv;
        wmx = fmaf(xx, s, wmx); wmy = fmaf(xy, s, wmy);
        wmz = fmaf(xz, s, wmz); wmw = fmaf(xw, s, wmw);
        if (mk[k] > 0.5f) {
            mxx = fmaxf(mxx, xx); mxy = fmaxf(mxy, xy);
            mxz = fmaxf(mxz, xz); mxw = fmaxf(mxw, xw);
        }
    }
    if (!hasany) { mxx = mxy = mxz = mxw = 0.f; }
    float4 wmv; wmv.x = wmx; wmv.y = wmy; wmv.z = wmz; wmv.w = wmw;
    float4 mxv; mxv.x = mxx; mxv.y = mxy; mxv.z = mxz; mxv.w = mxw;
    *(float4*)(out_wm + (size_t)bl*DD + d4) = wmv;
    *(float4*)(out_mx + (size_t)bl*DD + d4) = mxv;
    if (d4 == 0) {
        #pragma unroll
        for (int k = 0; k < KK; ++k) rowmask[bl*KK + k] = mk[k];
    }
    if (blockIdx.x == 0 && threadIdx.x < BB*KK) {
        int bb = threadIdx.x >> 2, kk2 = threadIdx.x & 3;
        float nv[KK];
        nsw_compute(sw, pres, bb, nv);
        f_nsw[threadIdx.x] = nv[kk2];
    }
}

// ---------------------------------------------------------------------------
// QKV GEMM, fragment-major register-direct (no LDS, no barriers).
//   C[32768,1536] = X @ Wqkv^T, fp16 in (both operands stored FRAGMENT-MAJOR
//   by their producers), fp32 accum, fp16 out routed into Q|K|V segments.
// Round-4's no-LDS design failed on uncoalesced fragment loads (64 cache
// lines/load); with fragment-major layout each wave fragment load is one
// contiguous 1KB global_load_dwordx4.  Demand model: max(VMEM-L1, MFMA)
// instead of the LDS path's sum (1590 cyc/block-tile -> 62 us floor).
//   - 128x128 tile, 4 waves (2Mx2N), wave-tile 64x64
//   - per K-tile/wave: 8 coalesced 1KB loads + 16 MFMA
//   - 2 register generations; compiler-counted vmcnt; zero barriers ->
//     waves free-run, no phase-lock; 3 blocks/CU (12 waves) for TLP.
// A-frags L1/L2-served across the 12 n-blocks (n-fastest XCD swizzle);
// W (1.5 MB) L2-resident per XCD.
__global__ __launch_bounds__(256, 3) void gemm_qkv_frag(
        const unsigned short* __restrict__ Af, const unsigned short* __restrict__ Wf,
        unsigned short* __restrict__ Cbase) {
    const int tid  = threadIdx.x;
    const int wave = tid >> 6, lane = tid & 63;
    // Bijective XCD swizzle (3072 blocks, 3072 % 8 == 0), n fastest.
    const int id = blockIdx.x;
    const int wg = (id & 7) * 384 + (id >> 3);
    const int m0 = (wg / 12) * 128;
    const int n0 = (wg % 12) * 128;
    const int wm = wave >> 1, wn = wave & 1;
    const int fr = lane & 15, q = lane >> 4;
    // Fragment streams: frag i of A covers rows [m0+wm*64+i*16, +16);
    // its K-tile-t slot is at ((mb*16 + t)*64 + lane)*8 ushorts.
    const unsigned short* ap[4];
    const unsigned short* bp[4];
    #pragma unroll
    for (int i = 0; i < 4; ++i) {
        const int mb = (m0 >> 4) + wm*4 + i;
        const int nb = (n0 >> 4) + wn*4 + i;
        ap[i] = Af + (size_t)mb*16*512 + lane*8;
        bp[i] = Wf + (size_t)nb*16*512 + lane*8;
    }
    hfrag a[2][4], b[2][4];
    f32x4 acc[4][4] = {};

#define LDGEN(g, t) do { \
        _Pragma("unroll") \
        for (int i = 0; i < 4; ++i) { \
            a[g][i] = *(const hfrag*)(ap[i] + (t)*512); \
            b[g][i] = *(const hfrag*)(bp[i] + (t)*512); \
        } } while (0)

    LDGEN(0, 0);
    LDGEN(1, 1);
    #pragma unroll
    for (int t = 0; t < 16; ++t) {
        const int g = t & 1;               // compile-time after full unroll
        __builtin_amdgcn_s_setprio(1);
        #pragma unroll
        for (int i = 0; i < 4; ++i)
            #pragma unroll
            for (int j = 0; j < 4; ++j)
                acc[i][j] = __builtin_amdgcn_mfma_f32_16x16x32_f16(a[g][i], b[g][j], acc[i][j], 0, 0, 0);
        __builtin_amdgcn_s_setprio(0);
        if (t < 14) LDGEN(g, t + 2);       // refill gen just consumed
    }
#undef LDGEN

    // Epilogue: route by 512-col segment into Q|K|V (M,512) row-major buffers.
    // Wave's 64-col span is 64-aligned -> never straddles a segment.
    const int gc0 = n0 + (wn << 6);
    const int seg = gc0 >> 9;
    unsigned short* Cs = Cbase + (size_t)seg * ((size_t)MM * 512);
    const int cb = gc0 & 511;
    #pragma unroll
    for (int mf = 0; mf < 4; ++mf) {
        const int grow = m0 + (wm << 6) + (mf << 4) + (q << 2);
        #pragma unroll
        for (int nf = 0; nf < 4; ++nf) {
            const int col = cb + (nf << 4) + fr;
            #pragma unroll
            for (int r = 0; r < 4; ++r)
                Cs[(size_t)(grow + r) * 512 + col] = f2h(acc[mf][nf][r]);
        }
    }
}

// ---------------------------------------------------------------------------
// Wo GEMM + swr-pooling, pipelined (unchanged from round 6).
__global__ __launch_bounds__(512, 4) void wo_gemm(
        const unsigned short* __restrict__ A,   // attn_out (MM,512) fp16
        const unsigned short* __restrict__ W,   // Wo (512,512) fp16
        const float* __restrict__ sw, const int* __restrict__ pres,
        const float* __restrict__ rmask, float* __restrict__ out_ap) {
    __shared__ __align__(16) unsigned short smem[36864];   // 3 bufs x 24 KiB
    const int tid  = threadIdx.x;
    const int wave = tid >> 6, lane = tid & 63;
    const int id = blockIdx.x;
    const int wg = (id & 7) * 64 + (id >> 3);
    const int m0 = (wg >> 2) * 256;            // 128 m-blocks
    const int n0 = (wg & 3) * 128;             // 4 n-blocks
    const int wm = wave >> 1, wn = wave & 1;
    const int fr = lane & 15, q = lane >> 4;
    const int srow = tid >> 2, scc = tid & 3;
    const int sswz = (scc ^ ((srow >> 1) & 3)) << 3;
    const unsigned short* Ag0 = A + (size_t)(m0 + srow)*512 + sswz;
    const unsigned short* Ag1 = Ag0 + (size_t)128*512;
    const unsigned short* Wg0 = W + (size_t)(n0 + srow)*512 + sswz;
    const int lA0 = tid << 3;
    const int lA1 = (tid + 512) << 3;
    int aoff[4], boff[4];
    #pragma unroll
    for (int mf = 0; mf < 4; ++mf) {
        int row = (wm << 6) + (mf << 4) + fr;
        aoff[mf] = (row << 5) + ((q ^ ((row >> 1) & 3)) << 3);
    }
    #pragma unroll
    for (int nf = 0; nf < 4; ++nf) {
        int row = (wn << 6) + (nf << 4) + fr;
        boff[nf] = (row << 5) + ((q ^ ((row >> 1) & 3)) << 3);
    }
    f32x4 acc[4][4] = {};

#define VMWAIT(N) asm volatile("s_waitcnt vmcnt(" #N ")" ::: "memory")
#define STAGE(tt) do { unsigned short* _d = smem + ((tt) % 3) * 12288; \
        const int _ko = (tt) << 5; \
        glds16(Ag0 + _ko, _d + lA0); glds16(Ag1 + _ko, _d + lA1); \
        glds16(Wg0 + _ko, _d + 8192 + lA0); } while (0)
#define MFROW(ai, areg) \
        acc[ai][0] = __builtin_amdgcn_mfma_f32_16x16x32_f16(areg, b0, acc[ai][0], 0, 0, 0); \
        acc[ai][1] = __builtin_amdgcn_mfma_f32_16x16x32_f16(areg, b1, acc[ai][1], 0, 0, 0); \
        acc[ai][2] = __builtin_amdgcn_mfma_f32_16x16x32_f16(areg, b2, acc[ai][2], 0, 0, 0); \
        acc[ai][3] = __builtin_amdgcn_mfma_f32_16x16x32_f16(areg, b3, acc[ai][3], 0, 0, 0);
#define TILE(t, STG, VM) do { \
        const unsigned short* _Ab = smem + ((t) % 3) * 12288; \
        const unsigned short* _Bb = _Ab + 8192; \
        VMWAIT(VM); \
        __builtin_amdgcn_s_barrier(); \
        __builtin_amdgcn_sched_barrier(0); \
        hfrag b0 = *(const hfrag*)(_Bb + boff[0]); \
        hfrag b1 = *(const hfrag*)(_Bb + boff[1]); \
        hfrag b2 = *(const hfrag*)(_Bb + boff[2]); \
        hfrag b3 = *(const hfrag*)(_Bb + boff[3]); \
        hfrag a0_ = *(const hfrag*)(_Ab + aoff[0]); \
        hfrag a1_ = *(const hfrag*)(_Ab + aoff[1]); \
        hfrag a2_ = *(const hfrag*)(_Ab + aoff[2]); \
        hfrag a3_ = *(const hfrag*)(_Ab + aoff[3]); \
        if (STG) STAGE((t) + 2); \
        __builtin_amdgcn_s_setprio(1); \
        MFROW(0, a0_) MFROW(1, a1_) MFROW(2, a2_) MFROW(3, a3_) \
        __builtin_amdgcn_s_setprio(0); \
    } while (0)

    STAGE(0); STAGE(1);
    #pragma unroll
    for (int t = 0; t < 14; ++t) TILE(t, 1, 3);
    TILE(14, 0, 3);
    TILE(15, 0, 0);
#undef TILE
#undef MFROW
#undef STAGE
#undef VMWAIT

    const int b = (m0 >> 2) >> 10;
    float nv[KK];
    nsw_compute(sw, pres, b, nv);
    #pragma unroll
    for (int mf = 0; mf < 4; ++mf) {
        const int grow = m0 + (wm << 6) + (mf << 4) + (q << 2);
        const int bl = grow >> 2;
        float s4[KK]; float ssum = 0.f;
        #pragma unroll
        for (int k = 0; k < KK; ++k) { s4[k] = nv[k] * rmask[bl*4 + k]; ssum += s4[k]; }
        const float inv = 1.f / fmaxf(ssum, EPSF);
        #pragma unroll
        for (int nf = 0; nf < 4; ++nf) {
            const int col = n0 + (wn << 6) + (nf << 4) + fr;
            float ap = 0.f;
            #pragma unroll
            for (int r = 0; r < KK; ++r) ap = fmaf(s4[r]*inv, acc[mf][nf][r], ap);
            out_ap[(size_t)bl*512 + col] = ap;
        }
    }
}

// ---------------------------------------------------------------------------
// LN1 over [ap|wm|mx] (1536) per bl (unchanged from round 6).
__global__ __launch_bounds__(256) void ln1_kernel(
        const float* __restrict__ ap, const float* __restrict__ wm,
        const float* __restrict__ mx, const float* __restrict__ g,
        const float* __restrict__ bvec, unsigned short* __restrict__ hin) {
    const int bl = blockIdx.x * 4 + (threadIdx.x >> 6);
    const int lane = threadIdx.x & 63;
    const int c0 = lane * 8;
    float4 v[3][2];
    const float* srcs[3] = { ap + (size_t)bl*512 + c0,
                             wm + (size_t)bl*512 + c0,
                             mx + (size_t)bl*512 + c0 };
    float s = 0.f, s2 = 0.f;
    #pragma unroll
    for (int sg = 0; sg < 3; ++sg) {
        v[sg][0] = *(const float4*)(srcs[sg]);
        v[sg][1] = *(const float4*)(srcs[sg] + 4);
        #pragma unroll
        for (int e = 0; e < 8; ++e) {
            float x = ((const float*)v[sg])[e];
            s += x; s2 += x*x;
        }
    }
    #pragma unroll
    for (int o = 1; o < 64; o <<= 1) {
        s  += __shfl_xor(s,  o, 64);
        s2 += __shfl_xor(s2, o, 64);
    }
    const float mu = s * (1.f/(float)D3);
    const float var = s2 * (1.f/(float)D3) - mu*mu;
    const float rstd = rsqrtf(var + LN_EPSF);
    #pragma unroll
    for (int sg = 0; sg < 3; ++sg) {
        const int gofs = sg*512 + c0;
        #pragma unroll
        for (int h = 0; h < 2; ++h) {
            float4 g4 = *(const float4*)(g + gofs + h*4);
            float4 b4 = *(const float4*)(bvec + gofs + h*4);
            const float* sv = (const float*)&v[sg][h];
            ushort4 o4;
            o4.x = f2h((sv[0]-mu)*rstd*g4.x + b4.x);
            o4.y = f2h((sv[1]-mu)*rstd*g4.y + b4.y);
            o4.z = f2h((sv[2]-mu)*rstd*g4.z + b4.z);
            o4.w = f2h((sv[3]-mu)*rstd*g4.w + b4.w);
            *(ushort4*)(hin + (size_t)bl*D3 + gofs + h*4) = o4;
        }
    }
}

// ---------------------------------------------------------------------------
// Wg1 + GELU, pipelined (unchanged from round 6).
__global__ __launch_bounds__(256, 3) void gemm_g1(
        const unsigned short* __restrict__ A, const unsigned short* __restrict__ W,
        unsigned short* __restrict__ C, const float* __restrict__ bias) {
    __shared__ __align__(16) unsigned short smem[24576];   // 3 bufs x 16 KiB
    const int tid  = threadIdx.x;
    const int wave = tid >> 6, lane = tid & 63;
    const int id = blockIdx.x;
    const int wg = (id & 7) * 32 + (id >> 3);
    const int m0 = (wg >> 2) * 128;
    const int n0 = (wg & 3) * 128;
    const int wm = wave >> 1, wn = wave & 1;
    const int fr = lane & 15, q = lane >> 4;
    const int srow = tid >> 2, scc = tid & 3;
    const int sswz = (scc ^ ((srow >> 1) & 3)) << 3;
    const unsigned short* Ag0 = A + (size_t)(m0 + srow)*D3 + sswz;
    const unsigned short* Ag1 = Ag0 + (size_t)64*D3;
    const unsigned short* Wg0 = W + (size_t)(n0 + srow)*D3 + sswz;
    const unsigned short* Wg1p = Wg0 + (size_t)64*D3;
    const int lA0 = tid << 3;
    const int lA1 = (tid + 256) << 3;
    int aoff[4], boff[4];
    #pragma unroll
    for (int mf = 0; mf < 4; ++mf) {
        int row = (wm << 6) + (mf << 4) + fr;
        aoff[mf] = (row << 5) + ((q ^ ((row >> 1) & 3)) << 3);
    }
    #pragma unroll
    for (int nf = 0; nf < 4; ++nf) {
        int row = (wn << 6) + (nf << 4) + fr;
        boff[nf] = (row << 5) + ((q ^ ((row >> 1) & 3)) << 3);
    }
    f32x4 acc[4][4] = {};

#define VMWAIT(N) asm volatile("s_waitcnt vmcnt(" #N ")" ::: "memory")
#define STAGE(tt) do { unsigned short* _d = smem + ((tt) % 3) * 8192; \
        const int _ko = (tt) << 5; \
        glds16(Ag0 + _ko, _d + lA0); glds16(Ag1 + _ko, _d + lA1); \
        glds16(Wg0 + _ko, _d + 4096 + lA0); glds16(Wg1p + _ko, _d + 4096 + lA1); } while (0)
#define MFROW(ai, areg) \
        acc[ai][0] = __builtin_amdgcn_mfma_f32_16x16x32_f16(areg, b0, acc[ai][0], 0, 0, 0); \
        acc[ai][1] = __builtin_amdgcn_mfma_f32_16x16x32_f16(areg, b1, acc[ai][1], 0, 0, 0); \
        acc[ai][2] = __builtin_amdgcn_mfma_f32_16x16x32_f16(areg, b2, acc[ai][2], 0, 0, 0); \
        acc[ai][3] = __builtin_amdgcn_mfma_f32_16x16x32_f16(areg, b3, acc[ai][3], 0, 0, 0);
#define TILE(t, STG, VM) do { \
        const unsigned short* _Ab = smem + ((t) % 3) * 8192; \
        const unsigned short* _Bb = _Ab + 4096; \
        VMWAIT(VM); \
        __builtin_amdgcn_s_barrier(); \
        __builtin_amdgcn_sched_barrier(0); \
        hfrag b0 = *(const hfrag*)(_Bb + boff[0]); \
        hfrag b1 = *(const hfrag*)(_Bb + boff[1]); \
        hfrag b2 = *(const hfrag*)(_Bb + boff[2]); \
        hfrag b3 = *(const hfrag*)(_Bb + boff[3]); \
        hfrag a0_ = *(const hfrag*)(_Ab + aoff[0]); \
        hfrag a1_ = *(const hfrag*)(_Ab + aoff[1]); \
        hfrag a2_ = *(const hfrag*)(_Ab + aoff[2]); \
        hfrag a3_ = *(const hfrag*)(_Ab + aoff[3]); \
        if (STG) STAGE((t) + 2); \
        __builtin_amdgcn_s_setprio(1); \
        MFROW(0, a0_) MFROW(1, a1_) MFROW(2, a2_) MFROW(3, a3_) \
        __builtin_amdgcn_s_setprio(0); \
    } while (0)

    STAGE(0); STAGE(1);
    #pragma unroll 3
    for (int t = 0; t < 46; ++t) TILE(t, 1, 4);
    TILE(46, 0, 4);
    TILE(47, 0, 0);
#undef TILE
#undef MFROW
#undef STAGE
#undef VMWAIT

    #pragma unroll
    for (int mf = 0; mf < 4; ++mf) {
        const int grow = m0 + (wm << 6) + (mf << 4) + (q << 2);
        #pragma unroll
        for (int nf = 0; nf < 4; ++nf) {
            const int col = n0 + (wn << 6) + (nf << 4) + fr;
            const float bv = bias[col];
            #pragma unroll
            for (int r = 0; r < 4; ++r) {
                float v = acc[mf][nf][r] + bv;
                v = 0.5f * v * (1.f + erff(v * 0.70710678118654752f));
                C[(size_t)(grow + r) * 512 + col] = f2h(v);
            }
        }
    }
}

// ---------------------------------------------------------------------------
// Wg2 GEMM + gate + fusion (pointwise), pipelined (unchanged from round 6).
__global__ __launch_bounds__(256, 3) void wg2_gemm(
        const unsigned short* __restrict__ A,   // gelu(h) (BL,512) fp16
        const unsigned short* __restrict__ W,   // Wg2 (512,512) fp16
        const float* __restrict__ bg2,
        const float* __restrict__ in_ap, const float* __restrict__ in_wm,
        const float* __restrict__ in_mx, float* __restrict__ pre) {
    __shared__ __align__(16) unsigned short smem[24576];   // 3 bufs x 16 KiB
    const int tid  = threadIdx.x;
    const int wave = tid >> 6, lane = tid & 63;
    const int id = blockIdx.x;
    const int wg = (id & 7) * 32 + (id >> 3);
    const int m0 = (wg >> 2) * 128;            // 64 m-blocks
    const int n0 = (wg & 3) * 128;             // 4 n-blocks
    const int wm = wave >> 1, wn = wave & 1;
    const int fr = lane & 15, q = lane >> 4;
    const int srow = tid >> 2, scc = tid & 3;
    const int sswz = (scc ^ ((srow >> 1) & 3)) << 3;
    const unsigned short* Ag0 = A + (size_t)(m0 + srow)*512 + sswz;
    const unsigned short* Ag1 = Ag0 + (size_t)64*512;
    const unsigned short* Wg0 = W + (size_t)(n0 + srow)*512 + sswz;
    const unsigned short* Wg1p = Wg0 + (size_t)64*512;
    const int lA0 = tid << 3;
    const int lA1 = (tid + 256) << 3;
    int aoff[4], boff[4];
    #pragma unroll
    for (int mf = 0; mf < 4; ++mf) {
        int row = (wm << 6) + (mf << 4) + fr;
        aoff[mf] = (row << 5) + ((q ^ ((row >> 1) & 3)) << 3);
    }
    #pragma unroll
    for (int nf = 0; nf < 4; ++nf) {
        int row = (wn << 6) + (nf << 4) + fr;
        boff[nf] = (row << 5) + ((q ^ ((row >> 1) & 3)) << 3);
    }
    f32x4 acc[4][4] = {};

#define VMWAIT(N) asm volatile("s_waitcnt vmcnt(" #N ")" ::: "memory")
#define STAGE(tt) do { unsigned short* _d = smem + ((tt) % 3) * 8192; \
        const int _ko = (tt) << 5; \
        glds16(Ag0 + _ko, _d + lA0); glds16(Ag1 + _ko, _d + lA1); \
        glds16(Wg0 + _ko, _d + 4096 + lA0); glds16(Wg1p + _ko, _d + 4096 + lA1); } while (0)
#define MFROW(ai, areg) \
        acc[ai][0] = __builtin_amdgcn_mfma_f32_16x16x32_f16(areg, b0, acc[ai][0], 0, 0, 0); \
        acc[ai][1] = __builtin_amdgcn_mfma_f32_16x16x32_f16(areg, b1, acc[ai][1], 0, 0, 0); \
        acc[ai][2] = __builtin_amdgcn_mfma_f32_16x16x32_f16(areg, b2, acc[ai][2], 0, 0, 0); \
        acc[ai][3] = __builtin_amdgcn_mfma_f32_16x16x32_f16(areg, b3, acc[ai][3], 0, 0, 0);
#define TILE(t, STG, VM) do { \
        const unsigned short* _Ab = smem + ((t) % 3) * 8192; \
        const unsigned short* _Bb = _Ab + 4096; \
        VMWAIT(VM); \
        __builtin_amdgcn_s_barrier(); \
        __builtin_amdgcn_sched_barrier(0); \
        hfrag b0 = *(const hfrag*)(_Bb + boff[0]); \
        hfrag b1 = *(const hfrag*)(_Bb + boff[1]); \
        hfrag b2 = *(const hfrag*)(_Bb + boff[2]); \
        hfrag b3 = *(const hfrag*)(_Bb + boff[3]); \
        hfrag a0_ = *(const hfrag*)(_Ab + aoff[0]); \
        hfrag a1_ = *(const hfrag*)(_Ab + aoff[1]); \
        hfrag a2_ = *(const hfrag*)(_Ab + aoff[2]); \
        hfrag a3_ = *(const hfrag*)(_Ab + aoff[3]); \
        if (STG) STAGE((t) + 2); \
        __builtin_amdgcn_s_setprio(1); \
        MFROW(0, a0_) MFROW(1, a1_) MFROW(2, a2_) MFROW(3, a3_) \
        __builtin_amdgcn_s_setprio(0); \
    } while (0)

    STAGE(0); STAGE(1);
    #pragma unroll
    for (int t = 0; t < 14; ++t) TILE(t, 1, 4);
    TILE(14, 0, 4);
    TILE(15, 0, 0);
#undef TILE
#undef MFROW
#undef STAGE
#undef VMWAIT

    #pragma unroll
    for (int mf = 0; mf < 4; ++mf) {
        const int grow = m0 + (wm << 6) + (mf << 4) + (q << 2);
        #pragma unroll
        for (int nf = 0; nf < 4; ++nf) {
            const int col = n0 + (wn << 6) + (nf << 4) + fr;
            const float bv = bg2[col];
            #pragma unroll
            for (int r = 0; r < 4; ++r) {
                const int row = grow + r;
                float g = 1.f / (1.f + expf(-(acc[mf][nf][r] + bv)));
                float ap = in_ap[(size_t)row*512 + col];
                float wmv = in_wm[(size_t)row*512 + col];
                float mxv = in_mx[(size_t)row*512 + col];
                pre[(size_t)row*512 + col] = g*0.5f*(ap + wmv) + (1.f - g)*mxv + wmv;
            }
        }
    }
}

// ---------------------------------------------------------------------------
// Final LN over pre (512) per row (unchanged from round 6).
__global__ __launch_bounds__(256) void final_ln_kernel(
        const float* __restrict__ pre, const float* __restrict__ ng,
        const float* __restrict__ nb, float* __restrict__ fused) {
    const int row = blockIdx.x * 4 + (threadIdx.x >> 6);
    const int lane = threadIdx.x & 63;
    const int c0 = lane * 8;
    float4 p0 = *(const float4*)(pre + (size_t)row*512 + c0);
    float4 p1 = *(const float4*)(pre + (size_t)row*512 + c0 + 4);
    float s = 0.f, s2 = 0.f;
    const float* pv = (const float*)&p0;
    #pragma unroll
    for (int e = 0; e < 4; ++e) { s += pv[e]; s2 += pv[e]*pv[e]; }
    pv = (const float*)&p1;
    #pragma unroll
    for (int e = 0; e < 4; ++e) { s += pv[e]; s2 += pv[e]*pv[e]; }
    #pragma unroll
    for (int o = 1; o < 64; o <<= 1) {
        s  += __shfl_xor(s,  o, 64);
        s2 += __shfl_xor(s2, o, 64);
    }
    const float mu = s * (1.f/(float)DD);
    const float var = s2 * (1.f/(float)DD) - mu*mu;
    const float rstd = rsqrtf(var + LN_EPSF);
    float4 g0 = *(const float4*)(ng + c0), g1 = *(const float4*)(ng + c0 + 4);
    float4 b0 = *(const float4*)(nb + c0), b1 = *(const float4*)(nb + c0 + 4);
    float4 o0, o1;
    o0.x = (p0.x-mu)*rstd*g0.x + b0.x; o0.y = (p0.y-mu)*rstd*g0.y + b0.y;
    o0.z = (p0.z-mu)*rstd*g0.z + b0.z; o0.w = (p0.w-mu)*rstd*g0.w + b0.w;
    o1.x = (p1.x-mu)*rstd*g1.x + b1.x; o1.y = (p1.y-mu)*rstd*g1.y + b1.y;
    o1.z = (p1.z-mu)*rstd*g1.z + b1.z; o1.w = (p1.w-mu)*rstd*g1.w + b1.w;
    *(float4*)(fused + (size_t)row*512 + c0) = o0;
    *(float4*)(fused + (size_t)row*512 + c0 + 4) = o1;
}

// ---------------------------------------------------------------------------
// Per-(b,l) attention over K=4 states (unchanged from round 5).
__global__ __launch_bounds__(256) void attn_kernel(
        unsigned short* Qb /* in: q, out: attn_out */,
        const unsigned short* __restrict__ Kb, const unsigned short* __restrict__ Vb,
        const float* __restrict__ sw, const int* __restrict__ pres,
        const float* __restrict__ rowmask,
        float* __restrict__ attn_mean_out) {
    __shared__ float att[128];           // [h*16 + i*4 + j]
    __shared__ float lw[KK], mk[KK];
    int bl = blockIdx.x, b = bl >> 10, mb = bl * KK;
    int tid = threadIdx.x;
    if (tid < KK) {
        float nv[KK];
        nsw_compute(sw, pres, b, nv);
        lw[tid] = logf(fmaxf(nv[tid], EPSF));
        mk[tid] = rowmask[mb + tid];
    }
    __syncthreads();
    if (tid < 128) {
        int h = tid >> 4, i = (tid >> 2) & 3, j = tid & 3;
        const unsigned short* qp = Qb + (size_t)(mb + i)*DD + h*HD;
        const unsigned short* kp = Kb + (size_t)(mb + j)*DD + h*HD;
        float s = 0.f;
        #pragma unroll
        for (int c = 0; c < 8; ++c) {
            hfrag qv = *(const hfrag*)(qp + c*8);
            hfrag kv = *(const hfrag*)(kp + c*8);
            #pragma unroll
            for (int e = 0; e < 8; ++e)
                s = fmaf((float)qv[e], (float)kv[e], s);
        }
        float lg = s * SCALE + lw[j];
        att[tid] = (mk[j] > 0.5f) ? lg : -INFINITY;
    }
    __syncthreads();
    if (tid < 32) {
        int base = tid * 4;
        float l0 = att[base], l1 = att[base+1], l2 = att[base+2], l3 = att[base+3];
        float m = fmaxf(fmaxf(l0, l1), fmaxf(l2, l3));
        if (m == -INFINITY) {
            att[base] = att[base+1] = att[base+2] = att[base+3] = 0.f;
        } else {
            float e0 = expf(l0 - m), e1 = expf(l1 - m), e2 = expf(l2 - m), e3 = expf(l3 - m);
            float inv = 1.f / (e0 + e1 + e2 + e3);
            att[base] = e0*inv; att[base+1] = e1*inv; att[base+2] = e2*inv; att[base+3] = e3*inv;
        }
    }
    __syncthreads();
    if (tid < KK) {
        float s = 0.f;
        for (int hi = 0; hi < 32; ++hi) s += att[hi*4 + tid];
        attn_mean_out[(size_t)bl*KK + tid] = s * (1.f/32.f);
    }
    // PV: 4 rows x 512 cols as (i, d2-pair); coalesced ushort2 V reads.
    #pragma unroll
    for (int p = 0; p < 4; ++p) {
        int idx = p*256 + tid;               // 0..1023
        int i = idx >> 8, d2 = (idx & 255) << 1, h = d2 >> 6;
        float s0 = 0.f, s1 = 0.f;
        #pragma unroll
        for (int j = 0; j < KK; ++j) {
            float aj = att[h*16 + i*4 + j];
            ushort2 vv = *(const ushort2*)(Vb + (size_t)(mb + j)*DD + d2);
            s0 = fmaf(aj, h2f(vv.x), s0);
            s1 = fmaf(aj, h2f(vv.y), s1);
        }
        ushort2 o; o.x = f2h(s0); o.y = f2h(s1);
        *(ushort2*)(Qb + (size_t)(mb + i)*DD + d2) = o;
    }
}

// ---------------------------------------------------------------------------
extern "C" void kernel_launch(void* const* d_in, const int* in_sizes, int n_in,
                              void* d_out, int out_size, void* d_ws, size_t ws_size,
                              hipStream_t stream) {
    const float* SR      = (const float*)d_in[0];
    const int*   residue = (const int*)d_in[1];
    const float* sw      = (const float*)d_in[2];
    const int*   roles   = (const int*)d_in[3];
    const int*   pres    = (const int*)d_in[4];
    const float* role_emb= (const float*)d_in[5];
    const float* Wq      = (const float*)d_in[6];
    const float* Wk      = (const float*)d_in[7];
    const float* Wv      = (const float*)d_in[8];
    const float* Wo      = (const float*)d_in[9];
    const float* ln1_g   = (const float*)d_in[10];
    const float* ln1_b   = (const float*)d_in[11];
    const float* Wg1     = (const float*)d_in[12];
    const float* bg1     = (const float*)d_in[13];
    const float* Wg2     = (const float*)d_in[14];
    const float* bg2     = (const float*)d_in[15];
    const float* norm_g  = (const float*)d_in[16];
    const float* norm_b  = (const float*)d_in[17];

    float* out = (float*)d_out;
    const size_t BLD = (size_t)BL * DD;
    float* f_fused = out;
    float* f_ap    = out + BLD;
    float* f_wm    = out + 2*BLD;
    float* f_mx    = out + 3*BLD;
    float* f_am    = out + 4*BLD;
    float* f_nsw   = out + 4*BLD + (size_t)BL*KK;

    char* base = (char*)d_ws;
    const size_t MD2 = (size_t)MM * DD * 2;     // 32 MB per fp16 activation buffer
    unsigned short* Xh = (unsigned short*)(base);        // fragment-major X
    unsigned short* Qh = (unsigned short*)(base + MD2);       // Q|K|V contiguous:
    unsigned short* Kh = (unsigned short*)(base + 2*MD2);     //  QKV routing relies
    unsigned short* Vh = (unsigned short*)(base + 3*MD2);     //  on this layout
    unsigned short* Wb = (unsigned short*)(base + 4*MD2);     // 4 MB weights
    float* rmask = (float*)(base + 4*MD2 + (size_t)WTOT*2);
    unsigned short* AOh  = Qh;   // attn_out (in-place over q)
    unsigned short* Hin  = Vh;   // (B,L,1536) fp16 (V dead after attn)
    unsigned short* Hbuf = Xh;   // gelu(h) (B,L,512) fp16 (X dead after QKV)
    float* preb = (float*)Kh;    // pre-LN fusion (BL,512) fp32 (K dead after attn)
    const unsigned short* Wqkv = Wb;            // (1536,512) fragment-major
    const unsigned short* Woh  = Wb + 3*WSZ;
    const unsigned short* Wg1h = Wb + OG1;
    const unsigned short* Wg2h = Wb + OG2;

    dim3 blk(256);

    cvt_weights<<<WTOT/1024, blk, 0, stream>>>(Wq, Wk, Wv, Wo, Wg1, Wg2, Wb);
    buildx_kernel<<<(BL*128)/256, blk, 0, stream>>>(SR, residue, pres, roles, role_emb,
                                                    sw, Xh, rmask, f_wm, f_mx, f_nsw);

    // Fused QKV: fragment-major register-direct, no LDS/no barriers.
    gemm_qkv_frag<<<dim3(3072), blk, 0, stream>>>(Xh, Wqkv, Qh);

    attn_kernel<<<BL, blk, 0, stream>>>(Qh, Kh, Vh, sw, pres, rmask, f_am);

    // Wo + swr-pooling: pipelined 256x128, 512 blocks (2/CU).
    wo_gemm<<<dim3(512), dim3(512), 0, stream>>>(
        AOh, Woh, sw, pres, rmask, f_ap);

    // LN1 over [ap|wm|mx] -> hin fp16.
    ln1_kernel<<<dim3(BL/4), blk, 0, stream>>>(
        f_ap, f_wm, f_mx, ln1_g, ln1_b, Hin);

    // Wg1 + GELU: pipelined 128x128 kernel, 256 blocks.
    gemm_g1<<<dim3(256), blk, 0, stream>>>(Hin, Wg1h, Hbuf, bg1);

    // Wg2 + gate + fusion (pointwise): pipelined 128x128, 256 blocks.
    wg2_gemm<<<dim3(256), blk, 0, stream>>>(
        Hbuf, Wg2h, bg2, f_ap, f_wm, f_mx, preb);

    // Final LN -> fused.
    final_ln_kernel<<<dim3(BL/4), blk, 0, stream>>>(
        preb, norm_g, norm_b, f_fused);
}

// Round 8
// 314.250 us; speedup vs baseline: 1.2185x; 1.2185x over previous
//
#include <hip/hip_runtime.h>
#include <math.h>

// Problem constants
#define BB 8
#define KK 4
#define LL 1024
#define DD 512
#define HD 64
#define D3 1536
#define MM (BB*LL*KK)   // 32768 rows for per-state GEMMs
#define BL (BB*LL)      // 8192 (b,l) positions
#define SCALE 0.125f
#define EPSF 1e-8f
#define LN_EPSF 1e-5f

typedef _Float16 hfrag __attribute__((ext_vector_type(8)));
typedef float f32x4 __attribute__((ext_vector_type(4)));

__device__ __forceinline__ unsigned short f2h(float f) {
    _Float16 h = (_Float16)f;
    unsigned short u; __builtin_memcpy(&u, &h, 2); return u;
}
__device__ __forceinline__ float h2f(unsigned short u) {
    _Float16 h; __builtin_memcpy(&h, &u, 2); return (float)h;
}

__device__ __forceinline__ void glds16(const unsigned short* g, unsigned short* l) {
    __builtin_amdgcn_global_load_lds(
        (const __attribute__((address_space(1))) void*)g,
        (__attribute__((address_space(3))) void*)l, 16, 0, 0);
}

// Inline nsw: normalized state weight for (b,k) from sw/pres (32 elems, L2-hot)
__device__ __forceinline__ void nsw_compute(const float* sw, const int* pres,
                                            int b, float* nswv) {
    float w[KK], pr[KK]; float denom = 0.f, ps = 0.f;
    #pragma unroll
    for (int k = 0; k < KK; ++k) {
        pr[k] = pres[b*KK + k] ? 1.f : 0.f;
        w[k]  = sw[b*KK + k] * pr[k];
        denom += w[k]; ps += pr[k];
    }
    #pragma unroll
    for (int k = 0; k < KK; ++k)
        nswv[k] = (denom > EPSF) ? w[k] / fmaxf(denom, EPSF)
                                 : pr[k] / fmaxf(ps, 1.f);
}

// ---------------------------------------------------------------------------
// Fused fp32 -> fp16 weight conversion (row-major, round-5 version reverted:
// fragment-major experiment regressed QKV 62->90 us via L1-port serialization)
#define WSZ 262144          // 512*512
#define OG1 1048576         // start of Wg1 (512*1536)
#define OG2 1835008         // start of Wg2
#define WTOT 2097152
__global__ __launch_bounds__(256) void cvt_weights(
        const float* __restrict__ Wq, const float* __restrict__ Wk,
        const float* __restrict__ Wv, const float* __restrict__ Wo,
        const float* __restrict__ Wg1, const float* __restrict__ Wg2,
        unsigned short* __restrict__ dst) {
    int t = blockIdx.x * 256 + threadIdx.x;   // one float4 per thread
    int e = t * 4;
    const float* src; int off;
    if      (e < WSZ)    { src = Wq;  off = e; }
    else if (e < 2*WSZ)  { src = Wk;  off = e - WSZ; }
    else if (e < 3*WSZ)  { src = Wv;  off = e - 2*WSZ; }
    else if (e < OG1)    { src = Wo;  off = e - 3*WSZ; }
    else if (e < OG2)    { src = Wg1; off = e - OG1; }
    else                 { src = Wg2; off = e - OG2; }
    float4 v = *(const float4*)(src + off);
    ushort4 o;
    o.x = f2h(v.x); o.y = f2h(v.y); o.z = f2h(v.z); o.w = f2h(v.w);
    *(ushort4*)(dst + e) = o;
}

// ---------------------------------------------------------------------------
// Build x (fp16, row-major) + weighted_mean/max_feat (fp32, exact) + rowmask
// + f_nsw.  (round-5 version reverted)
__global__ __launch_bounds__(256) void buildx_kernel(
        const float* __restrict__ SR, const int* __restrict__ residue,
        const int* __restrict__ pres, const int* __restrict__ roles,
        const float* __restrict__ role_emb, const float* __restrict__ sw,
        unsigned short* __restrict__ Xh, float* __restrict__ rowmask,
        float* __restrict__ out_wm, float* __restrict__ out_mx,
        float* __restrict__ f_nsw) {
    int t  = blockIdx.x * 256 + threadIdx.x;
    int bl = t >> 7;
    int d4 = (t & 127) << 2;
    int b  = bl >> 10, l = bl & 1023;
    float nswv[KK];
    nsw_compute(sw, pres, b, nswv);
    float mk[KK], swr[KK];
    float ssum = 0.f, many = 0.f;
    #pragma unroll
    for (int k = 0; k < KK; ++k) {
        int bk = b*KK + k;
        bool valid = (residue[(size_t)bk*LL + l] != 0) && (pres[bk] != 0);
        mk[k]  = valid ? 1.f : 0.f;
        swr[k] = nswv[k] * mk[k];
        ssum += swr[k]; many += mk[k];
    }
    float inv = 1.f / fmaxf(ssum, EPSF);
    bool hasany = many > 0.5f;
    float wmx = 0.f, wmy = 0.f, wmz = 0.f, wmw = 0.f;
    float mxx = -1e9f, mxy = -1e9f, mxz = -1e9f, mxw = -1e9f;
    #pragma unroll
    for (int k = 0; k < KK; ++k) {
        int bk = b*KK + k;
        int role = roles[bk]; if (role < 0) role = 0;
        float4 sr = *(const float4*)(SR + ((size_t)bk*LL + l)*DD + d4);
        float4 re = *(const float4*)(role_emb + (size_t)role*DD + d4);
        float xx = (sr.x + re.x)*mk[k], xy = (sr.y + re.y)*mk[k];
        float xz = (sr.z + re.z)*mk[k], xw = (sr.w + re.w)*mk[k];
        ushort4 xs; xs.x = f2h(xx); xs.y = f2h(xy); xs.z = f2h(xz); xs.w = f2h(xw);
        *(ushort4*)(Xh + (size_t)(bl*KK + k)*DD + d4) = xs;
        float s = swr[k]*inv;
        wmx = fmaf(xx, s, wmx); wmy = fmaf(xy, s, wmy);
        wmz = fmaf(xz, s, wmz); wmw = fmaf(xw, s, wmw);
        if (mk[k] > 0.5f) {
            mxx = fmaxf(mxx, xx); mxy = fmaxf(mxy, xy);
            mxz = fmaxf(mxz, xz); mxw = fmaxf(mxw, xw);
        }
    }
    if (!hasany) { mxx = mxy = mxz = mxw = 0.f; }
    float4 wmv; wmv.x = wmx; wmv.y = wmy; wmv.z = wmz; wmv.w = wmw;
    float4 mxv; mxv.x = mxx; mxv.y = mxy; mxv.z = mxz; mxv.w = mxw;
    *(float4*)(out_wm + (size_t)bl*DD + d4) = wmv;
    *(float4*)(out_mx + (size_t)bl*DD + d4) = mxv;
    if (d4 == 0) {
        #pragma unroll
        for (int k = 0; k < KK; ++k) rowmask[bl*KK + k] = mk[k];
    }
    if (blockIdx.x == 0 && threadIdx.x < BB*KK) {
        int bb = threadIdx.x >> 2, kk2 = threadIdx.x & 3;
        float nv[KK];
        nsw_compute(sw, pres, bb, nv);
        f_nsw[threadIdx.x] = nv[kk2];
    }
}

// ---------------------------------------------------------------------------
// QKV GEMM: round-3 verified LDS kernel (62 us), reverted byte-identical.
__global__ __launch_bounds__(512, 4) void gemm_qkv_8p(
        const unsigned short* __restrict__ A, const unsigned short* __restrict__ W,
        unsigned short* __restrict__ Cbase) {
    __shared__ __align__(16) unsigned short smem[36864];   // 3 bufs x 24 KiB
    const int tid  = threadIdx.x;
    const int wave = tid >> 6, lane = tid & 63;
    const int id = blockIdx.x;
    const int wg = (id & 7) * 192 + (id >> 3);
    const int m0 = (wg / 12) * 256;
    const int n0 = (wg % 12) * 128;
    const int wm = wave >> 1, wn = wave & 1;   // 4Mx2N wave grid
    const int fr = lane & 15, q = lane >> 4;
    const int srow = tid >> 2, scc = tid & 3;
    const int sswz = (scc ^ ((srow >> 1) & 3)) << 3;
    const unsigned short* Ag0 = A + (size_t)(m0 + srow)*512 + sswz;
    const unsigned short* Ag1 = Ag0 + (size_t)128*512;
    const unsigned short* Wg0 = W + (size_t)(n0 + srow)*512 + sswz;
    const int lA0 = tid << 3;
    const int lA1 = (tid + 512) << 3;
    int aoff[4], boff[4];
    #pragma unroll
    for (int mf = 0; mf < 4; ++mf) {
        int row = (wm << 6) + (mf << 4) + fr;
        aoff[mf] = (row << 5) + ((q ^ ((row >> 1) & 3)) << 3);
    }
    #pragma unroll
    for (int nf = 0; nf < 4; ++nf) {
        int row = (wn << 6) + (nf << 4) + fr;
        boff[nf] = (row << 5) + ((q ^ ((row >> 1) & 3)) << 3);
    }
    f32x4 acc[4][4] = {};

#define VMWAIT(N) asm volatile("s_waitcnt vmcnt(" #N ")" ::: "memory")
#define STAGE(tt) do { unsigned short* _d = smem + ((tt) % 3) * 12288; \
        const int _ko = (tt) << 5; \
        glds16(Ag0 + _ko, _d + lA0); glds16(Ag1 + _ko, _d + lA1); \
        glds16(Wg0 + _ko, _d + 8192 + lA0); } while (0)
#define MFROW(ai, areg) \
        acc[ai][0] = __builtin_amdgcn_mfma_f32_16x16x32_f16(areg, b0, acc[ai][0], 0, 0, 0); \
        acc[ai][1] = __builtin_amdgcn_mfma_f32_16x16x32_f16(areg, b1, acc[ai][1], 0, 0, 0); \
        acc[ai][2] = __builtin_amdgcn_mfma_f32_16x16x32_f16(areg, b2, acc[ai][2], 0, 0, 0); \
        acc[ai][3] = __builtin_amdgcn_mfma_f32_16x16x32_f16(areg, b3, acc[ai][3], 0, 0, 0);
#define TILE(t, STG, VM) do { \
        const unsigned short* _Ab = smem + ((t) % 3) * 12288; \
        const unsigned short* _Bb = _Ab + 8192; \
        VMWAIT(VM); \
        __builtin_amdgcn_s_barrier(); \
        __builtin_amdgcn_sched_barrier(0); \
        hfrag b0 = *(const hfrag*)(_Bb + boff[0]); \
        hfrag b1 = *(const hfrag*)(_Bb + boff[1]); \
        hfrag b2 = *(const hfrag*)(_Bb + boff[2]); \
        hfrag b3 = *(const hfrag*)(_Bb + boff[3]); \
        hfrag a0_ = *(const hfrag*)(_Ab + aoff[0]); \
        hfrag a1_ = *(const hfrag*)(_Ab + aoff[1]); \
        hfrag a2_ = *(const hfrag*)(_Ab + aoff[2]); \
        hfrag a3_ = *(const hfrag*)(_Ab + aoff[3]); \
        if (STG) STAGE((t) + 2); \
        __builtin_amdgcn_s_setprio(1); \
        MFROW(0, a0_) MFROW(1, a1_) MFROW(2, a2_) MFROW(3, a3_) \
        __builtin_amdgcn_s_setprio(0); \
    } while (0)

    STAGE(0); STAGE(1);
    #pragma unroll
    for (int t = 0; t < 14; ++t) TILE(t, 1, 3);
    TILE(14, 0, 3);
    TILE(15, 0, 0);
#undef TILE
#undef MFROW
#undef STAGE
#undef VMWAIT

    const int gc0 = n0 + (wn << 6);
    const int seg = gc0 >> 9;
    unsigned short* Cs = Cbase + (size_t)seg * ((size_t)MM * 512);
    const int cb = gc0 & 511;
    #pragma unroll
    for (int mf = 0; mf < 4; ++mf) {
        const int grow = m0 + (wm << 6) + (mf << 4) + (q << 2);
        #pragma unroll
        for (int nf = 0; nf < 4; ++nf) {
            const int col = cb + (nf << 4) + fr;
            #pragma unroll
            for (int r = 0; r < 4; ++r)
                Cs[(size_t)(grow + r) * 512 + col] = f2h(acc[mf][nf][r]);
        }
    }
}

// ---------------------------------------------------------------------------
// Per-(b,l) attention + POOLED PV.  Algebraic fusion: per-state attn_out is
// only ever consumed as attn_pooled = sum_q swr'_q (AO_q @ Wo^T); Wo is
// linear and the valid mask is the per-state scalar inside swr', so we pool
// BEFORE Wo: wv[h,j] = sum_q swr'_q att[h,q,j]; pooled[d] = sum_j
// wv[h(d),j] V[j,d].  Output pooled (BL,512) fp16 -> 4x smaller Wo GEMM and
// no 32MB attn_out round-trip.
__global__ __launch_bounds__(256) void attn_kernel(
        const unsigned short* __restrict__ Qb, const unsigned short* __restrict__ Kb,
        const unsigned short* __restrict__ Vb,
        unsigned short* __restrict__ pooled,     // (BL,512) fp16
        const float* __restrict__ sw, const int* __restrict__ pres,
        const float* __restrict__ rowmask,
        float* __restrict__ attn_mean_out) {
    __shared__ float att[128];           // [h*16 + q*4 + j]
    __shared__ float wv[32];             // [h*4 + j]
    __shared__ float lw[KK], mk[KK], sp[KK];
    int bl = blockIdx.x, b = bl >> 10, mb = bl * KK;
    int tid = threadIdx.x;
    if (tid < KK) {
        float nv[KK];
        nsw_compute(sw, pres, b, nv);
        lw[tid] = logf(fmaxf(nv[tid], EPSF));
        float mkk[KK]; float ssum = 0.f;
        #pragma unroll
        for (int k = 0; k < KK; ++k) { mkk[k] = rowmask[mb + k]; ssum += nv[k]*mkk[k]; }
        mk[tid] = mkk[tid];
        sp[tid] = nv[tid]*mkk[tid] / fmaxf(ssum, EPSF);   // swr' (mask-absorbed)
    }
    __syncthreads();
    if (tid < 128) {
        int h = tid >> 4, i = (tid >> 2) & 3, j = tid & 3;
        const unsigned short* qp = Qb + (size_t)(mb + i)*DD + h*HD;
        const unsigned short* kp = Kb + (size_t)(mb + j)*DD + h*HD;
        float s = 0.f;
        #pragma unroll
        for (int c = 0; c < 8; ++c) {
            hfrag qv = *(const hfrag*)(qp + c*8);
            hfrag kv = *(const hfrag*)(kp + c*8);
            #pragma unroll
            for (int e = 0; e < 8; ++e)
                s = fmaf((float)qv[e], (float)kv[e], s);
        }
        float lg = s * SCALE + lw[j];
        att[tid] = (mk[j] > 0.5f) ? lg : -INFINITY;
    }
    __syncthreads();
    if (tid < 32) {
        int base = tid * 4;
        float l0 = att[base], l1 = att[base+1], l2 = att[base+2], l3 = att[base+3];
        float m = fmaxf(fmaxf(l0, l1), fmaxf(l2, l3));
        if (m == -INFINITY) {
            att[base] = att[base+1] = att[base+2] = att[base+3] = 0.f;
        } else {
            float e0 = expf(l0 - m), e1 = expf(l1 - m), e2 = expf(l2 - m), e3 = expf(l3 - m);
            float inv = 1.f / (e0 + e1 + e2 + e3);
            att[base] = e0*inv; att[base+1] = e1*inv; att[base+2] = e2*inv; att[base+3] = e3*inv;
        }
    }
    __syncthreads();
    if (tid < KK) {
        float s = 0.f;
        for (int hi = 0; hi < 32; ++hi) s += att[hi*4 + tid];
        attn_mean_out[(size_t)bl*KK + tid] = s * (1.f/32.f);
    }
    if (tid < 32) {
        int h = tid >> 2, j = tid & 3;
        wv[tid] = sp[0]*att[h*16 + 0*4 + j] + sp[1]*att[h*16 + 1*4 + j]
                + sp[2]*att[h*16 + 2*4 + j] + sp[3]*att[h*16 + 3*4 + j];
    }
    __syncthreads();
    // Pooled PV: one d2-pair per thread (256 x 2 = 512 cols).
    {
        int d2 = tid << 1, h = d2 >> 6;
        float s0 = 0.f, s1 = 0.f;
        #pragma unroll
        for (int j = 0; j < KK; ++j) {
            float aj = wv[h*4 + j];
            ushort2 vvv = *(const ushort2*)(Vb + (size_t)(mb + j)*DD + d2);
            s0 = fmaf(aj, h2f(vvv.x), s0);
            s1 = fmaf(aj, h2f(vvv.y), s1);
        }
        ushort2 o; o.x = f2h(s0); o.y = f2h(s1);
        *(ushort2*)(pooled + (size_t)bl*DD + d2) = o;
    }
}

// ---------------------------------------------------------------------------
// ap GEMM: f_ap = pooled @ Wo^T, (8192,512)x(512,512), pipelined 128x128,
// fp32 out.  Replaces the 4x-larger per-state wo_gemm (pool-before-Wo).
__global__ __launch_bounds__(256, 3) void ap_gemm(
        const unsigned short* __restrict__ A,   // pooled (BL,512) fp16
        const unsigned short* __restrict__ W,   // Wo (512,512) fp16
        float* __restrict__ out_ap) {
    __shared__ __align__(16) unsigned short smem[24576];   // 3 bufs x 16 KiB
    const int tid  = threadIdx.x;
    const int wave = tid >> 6, lane = tid & 63;
    const int id = blockIdx.x;
    const int wg = (id & 7) * 32 + (id >> 3);
    const int m0 = (wg >> 2) * 128;            // 64 m-blocks
    const int n0 = (wg & 3) * 128;             // 4 n-blocks
    const int wm = wave >> 1, wn = wave & 1;
    const int fr = lane & 15, q = lane >> 4;
    const int srow = tid >> 2, scc = tid & 3;
    const int sswz = (scc ^ ((srow >> 1) & 3)) << 3;
    const unsigned short* Ag0 = A + (size_t)(m0 + srow)*512 + sswz;
    const unsigned short* Ag1 = Ag0 + (size_t)64*512;
    const unsigned short* Wg0 = W + (size_t)(n0 + srow)*512 + sswz;
    const unsigned short* Wg1p = Wg0 + (size_t)64*512;
    const int lA0 = tid << 3;
    const int lA1 = (tid + 256) << 3;
    int aoff[4], boff[4];
    #pragma unroll
    for (int mf = 0; mf < 4; ++mf) {
        int row = (wm << 6) + (mf << 4) + fr;
        aoff[mf] = (row << 5) + ((q ^ ((row >> 1) & 3)) << 3);
    }
    #pragma unroll
    for (int nf = 0; nf < 4; ++nf) {
        int row = (wn << 6) + (nf << 4) + fr;
        boff[nf] = (row << 5) + ((q ^ ((row >> 1) & 3)) << 3);
    }
    f32x4 acc[4][4] = {};

#define VMWAIT(N) asm volatile("s_waitcnt vmcnt(" #N ")" ::: "memory")
#define STAGE(tt) do { unsigned short* _d = smem + ((tt) % 3) * 8192; \
        const int _ko = (tt) << 5; \
        glds16(Ag0 + _ko, _d + lA0); glds16(Ag1 + _ko, _d + lA1); \
        glds16(Wg0 + _ko, _d + 4096 + lA0); glds16(Wg1p + _ko, _d + 4096 + lA1); } while (0)
#define MFROW(ai, areg) \
        acc[ai][0] = __builtin_amdgcn_mfma_f32_16x16x32_f16(areg, b0, acc[ai][0], 0, 0, 0); \
        acc[ai][1] = __builtin_amdgcn_mfma_f32_16x16x32_f16(areg, b1, acc[ai][1], 0, 0, 0); \
        acc[ai][2] = __builtin_amdgcn_mfma_f32_16x16x32_f16(areg, b2, acc[ai][2], 0, 0, 0); \
        acc[ai][3] = __builtin_amdgcn_mfma_f32_16x16x32_f16(areg, b3, acc[ai][3], 0, 0, 0);
#define TILE(t, STG, VM) do { \
        const unsigned short* _Ab = smem + ((t) % 3) * 8192; \
        const unsigned short* _Bb = _Ab + 4096; \
        VMWAIT(VM); \
        __builtin_amdgcn_s_barrier(); \
        __builtin_amdgcn_sched_barrier(0); \
        hfrag b0 = *(const hfrag*)(_Bb + boff[0]); \
        hfrag b1 = *(const hfrag*)(_Bb + boff[1]); \
        hfrag b2 = *(const hfrag*)(_Bb + boff[2]); \
        hfrag b3 = *(const hfrag*)(_Bb + boff[3]); \
        hfrag a0_ = *(const hfrag*)(_Ab + aoff[0]); \
        hfrag a1_ = *(const hfrag*)(_Ab + aoff[1]); \
        hfrag a2_ = *(const hfrag*)(_Ab + aoff[2]); \
        hfrag a3_ = *(const hfrag*)(_Ab + aoff[3]); \
        if (STG) STAGE((t) + 2); \
        __builtin_amdgcn_s_setprio(1); \
        MFROW(0, a0_) MFROW(1, a1_) MFROW(2, a2_) MFROW(3, a3_) \
        __builtin_amdgcn_s_setprio(0); \
    } while (0)

    STAGE(0); STAGE(1);
    #pragma unroll
    for (int t = 0; t < 14; ++t) TILE(t, 1, 4);
    TILE(14, 0, 4);
    TILE(15, 0, 0);
#undef TILE
#undef MFROW
#undef STAGE
#undef VMWAIT

    #pragma unroll
    for (int mf = 0; mf < 4; ++mf) {
        const int grow = m0 + (wm << 6) + (mf << 4) + (q << 2);
        #pragma unroll
        for (int nf = 0; nf < 4; ++nf) {
            const int col = n0 + (wn << 6) + (nf << 4) + fr;
            #pragma unroll
            for (int r = 0; r < 4; ++r)
                out_ap[(size_t)(grow + r)*512 + col] = acc[mf][nf][r];
        }
    }
}

// ---------------------------------------------------------------------------
// LN1 over [ap|wm|mx] (1536) per bl (unchanged).
__global__ __launch_bounds__(256) void ln1_kernel(
        const float* __restrict__ ap, const float* __restrict__ wm,
        const float* __restrict__ mx, const float* __restrict__ g,
        const float* __restrict__ bvec, unsigned short* __restrict__ hin) {
    const int bl = blockIdx.x * 4 + (threadIdx.x >> 6);
    const int lane = threadIdx.x & 63;
    const int c0 = lane * 8;
    float4 v[3][2];
    const float* srcs[3] = { ap + (size_t)bl*512 + c0,
                             wm + (size_t)bl*512 + c0,
                             mx + (size_t)bl*512 + c0 };
    float s = 0.f, s2 = 0.f;
    #pragma unroll
    for (int sg = 0; sg < 3; ++sg) {
        v[sg][0] = *(const float4*)(srcs[sg]);
        v[sg][1] = *(const float4*)(srcs[sg] + 4);
        #pragma unroll
        for (int e = 0; e < 8; ++e) {
            float x = ((const float*)v[sg])[e];
            s += x; s2 += x*x;
        }
    }
    #pragma unroll
    for (int o = 1; o < 64; o <<= 1) {
        s  += __shfl_xor(s,  o, 64);
        s2 += __shfl_xor(s2, o, 64);
    }
    const float mu = s * (1.f/(float)D3);
    const float var = s2 * (1.f/(float)D3) - mu*mu;
    const float rstd = rsqrtf(var + LN_EPSF);
    #pragma unroll
    for (int sg = 0; sg < 3; ++sg) {
        const int gofs = sg*512 + c0;
        #pragma unroll
        for (int h = 0; h < 2; ++h) {
            float4 g4 = *(const float4*)(g + gofs + h*4);
            float4 b4 = *(const float4*)(bvec + gofs + h*4);
            const float* sv = (const float*)&v[sg][h];
            ushort4 o4;
            o4.x = f2h((sv[0]-mu)*rstd*g4.x + b4.x);
            o4.y = f2h((sv[1]-mu)*rstd*g4.y + b4.y);
            o4.z = f2h((sv[2]-mu)*rstd*g4.z + b4.z);
            o4.w = f2h((sv[3]-mu)*rstd*g4.w + b4.w);
            *(ushort4*)(hin + (size_t)bl*D3 + gofs + h*4) = o4;
        }
    }
}

// ---------------------------------------------------------------------------
// Wg1 + GELU, pipelined (unchanged).
__global__ __launch_bounds__(256, 3) void gemm_g1(
        const unsigned short* __restrict__ A, const unsigned short* __restrict__ W,
        unsigned short* __restrict__ C, const float* __restrict__ bias) {
    __shared__ __align__(16) unsigned short smem[24576];   // 3 bufs x 16 KiB
    const int tid  = threadIdx.x;
    const int wave = tid >> 6, lane = tid & 63;
    const int id = blockIdx.x;
    const int wg = (id & 7) * 32 + (id >> 3);
    const int m0 = (wg >> 2) * 128;
    const int n0 = (wg & 3) * 128;
    const int wm = wave >> 1, wn = wave & 1;
    const int fr = lane & 15, q = lane >> 4;
    const int srow = tid >> 2, scc = tid & 3;
    const int sswz = (scc ^ ((srow >> 1) & 3)) << 3;
    const unsigned short* Ag0 = A + (size_t)(m0 + srow)*D3 + sswz;
    const unsigned short* Ag1 = Ag0 + (size_t)64*D3;
    const unsigned short* Wg0 = W + (size_t)(n0 + srow)*D3 + sswz;
    const unsigned short* Wg1p = Wg0 + (size_t)64*D3;
    const int lA0 = tid << 3;
    const int lA1 = (tid + 256) << 3;
    int aoff[4], boff[4];
    #pragma unroll
    for (int mf = 0; mf < 4; ++mf) {
        int row = (wm << 6) + (mf << 4) + fr;
        aoff[mf] = (row << 5) + ((q ^ ((row >> 1) & 3)) << 3);
    }
    #pragma unroll
    for (int nf = 0; nf < 4; ++nf) {
        int row = (wn << 6) + (nf << 4) + fr;
        boff[nf] = (row << 5) + ((q ^ ((row >> 1) & 3)) << 3);
    }
    f32x4 acc[4][4] = {};

#define VMWAIT(N) asm volatile("s_waitcnt vmcnt(" #N ")" ::: "memory")
#define STAGE(tt) do { unsigned short* _d = smem + ((tt) % 3) * 8192; \
        const int _ko = (tt) << 5; \
        glds16(Ag0 + _ko, _d + lA0); glds16(Ag1 + _ko, _d + lA1); \
        glds16(Wg0 + _ko, _d + 4096 + lA0); glds16(Wg1p + _ko, _d + 4096 + lA1); } while (0)
#define MFROW(ai, areg) \
        acc[ai][0] = __builtin_amdgcn_mfma_f32_16x16x32_f16(areg, b0, acc[ai][0], 0, 0, 0); \
        acc[ai][1] = __builtin_amdgcn_mfma_f32_16x16x32_f16(areg, b1, acc[ai][1], 0, 0, 0); \
        acc[ai][2] = __builtin_amdgcn_mfma_f32_16x16x32_f16(areg, b2, acc[ai][2], 0, 0, 0); \
        acc[ai][3] = __builtin_amdgcn_mfma_f32_16x16x32_f16(areg, b3, acc[ai][3], 0, 0, 0);
#define TILE(t, STG, VM) do { \
        const unsigned short* _Ab = smem + ((t) % 3) * 8192; \
        const unsigned short* _Bb = _Ab + 4096; \
        VMWAIT(VM); \
        __builtin_amdgcn_s_barrier(); \
        __builtin_amdgcn_sched_barrier(0); \
        hfrag b0 = *(const hfrag*)(_Bb + boff[0]); \
        hfrag b1 = *(const hfrag*)(_Bb + boff[1]); \
        hfrag b2 = *(const hfrag*)(_Bb + boff[2]); \
        hfrag b3 = *(const hfrag*)(_Bb + boff[3]); \
        hfrag a0_ = *(const hfrag*)(_Ab + aoff[0]); \
        hfrag a1_ = *(const hfrag*)(_Ab + aoff[1]); \
        hfrag a2_ = *(const hfrag*)(_Ab + aoff[2]); \
        hfrag a3_ = *(const hfrag*)(_Ab + aoff[3]); \
        if (STG) STAGE((t) + 2); \
        __builtin_amdgcn_s_setprio(1); \
        MFROW(0, a0_) MFROW(1, a1_) MFROW(2, a2_) MFROW(3, a3_) \
        __builtin_amdgcn_s_setprio(0); \
    } while (0)

    STAGE(0); STAGE(1);
    #pragma unroll 3
    for (int t = 0; t < 46; ++t) TILE(t, 1, 4);
    TILE(46, 0, 4);
    TILE(47, 0, 0);
#undef TILE
#undef MFROW
#undef STAGE
#undef VMWAIT

    #pragma unroll
    for (int mf = 0; mf < 4; ++mf) {
        const int grow = m0 + (wm << 6) + (mf << 4) + (q << 2);
        #pragma unroll
        for (int nf = 0; nf < 4; ++nf) {
            const int col = n0 + (wn << 6) + (nf << 4) + fr;
            const float bv = bias[col];
            #pragma unroll
            for (int r = 0; r < 4; ++r) {
                float v = acc[mf][nf][r] + bv;
                v = 0.5f * v * (1.f + erff(v * 0.70710678118654752f));
                C[(size_t)(grow + r) * 512 + col] = f2h(v);
            }
        }
    }
}

// ---------------------------------------------------------------------------
// Wg2 GEMM + gate + fusion (pointwise), pipelined (unchanged).
__global__ __launch_bounds__(256, 3) void wg2_gemm(
        const unsigned short* __restrict__ A,   // gelu(h) (BL,512) fp16
        const unsigned short* __restrict__ W,   // Wg2 (512,512) fp16
        const float* __restrict__ bg2,
        const float* __restrict__ in_ap, const float* __restrict__ in_wm,
        const float* __restrict__ in_mx, float* __restrict__ pre) {
    __shared__ __align__(16) unsigned short smem[24576];   // 3 bufs x 16 KiB
    const int tid  = threadIdx.x;
    const int wave = tid >> 6, lane = tid & 63;
    const int id = blockIdx.x;
    const int wg = (id & 7) * 32 + (id >> 3);
    const int m0 = (wg >> 2) * 128;            // 64 m-blocks
    const int n0 = (wg & 3) * 128;             // 4 n-blocks
    const int wm = wave >> 1, wn = wave & 1;
    const int fr = lane & 15, q = lane >> 4;
    const int srow = tid >> 2, scc = tid & 3;
    const int sswz = (scc ^ ((srow >> 1) & 3)) << 3;
    const unsigned short* Ag0 = A + (size_t)(m0 + srow)*512 + sswz;
    const unsigned short* Ag1 = Ag0 + (size_t)64*512;
    const unsigned short* Wg0 = W + (size_t)(n0 + srow)*512 + sswz;
    const unsigned short* Wg1p = Wg0 + (size_t)64*512;
    const int lA0 = tid << 3;
    const int lA1 = (tid + 256) << 3;
    int aoff[4], boff[4];
    #pragma unroll
    for (int mf = 0; mf < 4; ++mf) {
        int row = (wm << 6) + (mf << 4) + fr;
        aoff[mf] = (row << 5) + ((q ^ ((row >> 1) & 3)) << 3);
    }
    #pragma unroll
    for (int nf = 0; nf < 4; ++nf) {
        int row = (wn << 6) + (nf << 4) + fr;
        boff[nf] = (row << 5) + ((q ^ ((row >> 1) & 3)) << 3);
    }
    f32x4 acc[4][4] = {};

#define VMWAIT(N) asm volatile("s_waitcnt vmcnt(" #N ")" ::: "memory")
#define STAGE(tt) do { unsigned short* _d = smem + ((tt) % 3) * 8192; \
        const int _ko = (tt) << 5; \
        glds16(Ag0 + _ko, _d + lA0); glds16(Ag1 + _ko, _d + lA1); \
        glds16(Wg0 + _ko, _d + 4096 + lA0); glds16(Wg1p + _ko, _d + 4096 + lA1); } while (0)
#define MFROW(ai, areg) \
        acc[ai][0] = __builtin_amdgcn_mfma_f32_16x16x32_f16(areg, b0, acc[ai][0], 0, 0, 0); \
        acc[ai][1] = __builtin_amdgcn_mfma_f32_16x16x32_f16(areg, b1, acc[ai][1], 0, 0, 0); \
        acc[ai][2] = __builtin_amdgcn_mfma_f32_16x16x32_f16(areg, b2, acc[ai][2], 0, 0, 0); \
        acc[ai][3] = __builtin_amdgcn_mfma_f32_16x16x32_f16(areg, b3, acc[ai][3], 0, 0, 0);
#define TILE(t, STG, VM) do { \
        const unsigned short* _Ab = smem + ((t) % 3) * 8192; \
        const unsigned short* _Bb = _Ab + 4096; \
        VMWAIT(VM); \
        __builtin_amdgcn_s_barrier(); \
        __builtin_amdgcn_sched_barrier(0); \
        hfrag b0 = *(const hfrag*)(_Bb + boff[0]); \
        hfrag b1 = *(const hfrag*)(_Bb + boff[1]); \
        hfrag b2 = *(const hfrag*)(_Bb + boff[2]); \
        hfrag b3 = *(const hfrag*)(_Bb + boff[3]); \
        hfrag a0_ = *(const hfrag*)(_Ab + aoff[0]); \
        hfrag a1_ = *(const hfrag*)(_Ab + aoff[1]); \
        hfrag a2_ = *(const hfrag*)(_Ab + aoff[2]); \
        hfrag a3_ = *(const hfrag*)(_Ab + aoff[3]); \
        if (STG) STAGE((t) + 2); \
        __builtin_amdgcn_s_setprio(1); \
        MFROW(0, a0_) MFROW(1, a1_) MFROW(2, a2_) MFROW(3, a3_) \
        __builtin_amdgcn_s_setprio(0); \
    } while (0)

    STAGE(0); STAGE(1);
    #pragma unroll
    for (int t = 0; t < 14; ++t) TILE(t, 1, 4);
    TILE(14, 0, 4);
    TILE(15, 0, 0);
#undef TILE
#undef MFROW
#undef STAGE
#undef VMWAIT

    #pragma unroll
    for (int mf = 0; mf < 4; ++mf) {
        const int grow = m0 + (wm << 6) + (mf << 4) + (q << 2);
        #pragma unroll
        for (int nf = 0; nf < 4; ++nf) {
            const int col = n0 + (wn << 6) + (nf << 4) + fr;
            const float bv = bg2[col];
            #pragma unroll
            for (int r = 0; r < 4; ++r) {
                const int row = grow + r;
                float g = 1.f / (1.f + expf(-(acc[mf][nf][r] + bv)));
                float ap = in_ap[(size_t)row*512 + col];
                float wmv = in_wm[(size_t)row*512 + col];
                float mxv = in_mx[(size_t)row*512 + col];
                pre[(size_t)row*512 + col] = g*0.5f*(ap + wmv) + (1.f - g)*mxv + wmv;
            }
        }
    }
}

// ---------------------------------------------------------------------------
// Final LN over pre (512) per row (unchanged).
__global__ __launch_bounds__(256) void final_ln_kernel(
        const float* __restrict__ pre, const float* __restrict__ ng,
        const float* __restrict__ nb, float* __restrict__ fused) {
    const int row = blockIdx.x * 4 + (threadIdx.x >> 6);
    const int lane = threadIdx.x & 63;
    const int c0 = lane * 8;
    float4 p0 = *(const float4*)(pre + (size_t)row*512 + c0);
    float4 p1 = *(const float4*)(pre + (size_t)row*512 + c0 + 4);
    float s = 0.f, s2 = 0.f;
    const float* pv = (const float*)&p0;
    #pragma unroll
    for (int e = 0; e < 4; ++e) { s += pv[e]; s2 += pv[e]*pv[e]; }
    pv = (const float*)&p1;
    #pragma unroll
    for (int e = 0; e < 4; ++e) { s += pv[e]; s2 += pv[e]*pv[e]; }
    #pragma unroll
    for (int o = 1; o < 64; o <<= 1) {
        s  += __shfl_xor(s,  o, 64);
        s2 += __shfl_xor(s2, o, 64);
    }
    const float mu = s * (1.f/(float)DD);
    const float var = s2 * (1.f/(float)DD) - mu*mu;
    const float rstd = rsqrtf(var + LN_EPSF);
    float4 g0 = *(const float4*)(ng + c0), g1 = *(const float4*)(ng + c0 + 4);
    float4 b0 = *(const float4*)(nb + c0), b1 = *(const float4*)(nb + c0 + 4);
    float4 o0, o1;
    o0.x = (p0.x-mu)*rstd*g0.x + b0.x; o0.y = (p0.y-mu)*rstd*g0.y + b0.y;
    o0.z = (p0.z-mu)*rstd*g0.z + b0.z; o0.w = (p0.w-mu)*rstd*g0.w + b0.w;
    o1.x = (p1.x-mu)*rstd*g1.x + b1.x; o1.y = (p1.y-mu)*rstd*g1.y + b1.y;
    o1.z = (p1.z-mu)*rstd*g1.z + b1.z; o1.w = (p1.w-mu)*rstd*g1.w + b1.w;
    *(float4*)(fused + (size_t)row*512 + c0) = o0;
    *(float4*)(fused + (size_t)row*512 + c0 + 4) = o1;
}

// ---------------------------------------------------------------------------
extern "C" void kernel_launch(void* const* d_in, const int* in_sizes, int n_in,
                              void* d_out, int out_size, void* d_ws, size_t ws_size,
                              hipStream_t stream) {
    const float* SR      = (const float*)d_in[0];
    const int*   residue = (const int*)d_in[1];
    const float* sw      = (const float*)d_in[2];
    const int*   roles   = (const int*)d_in[3];
    const int*   pres    = (const int*)d_in[4];
    const float* role_emb= (const float*)d_in[5];
    const float* Wq      = (const float*)d_in[6];
    const float* Wk      = (const float*)d_in[7];
    const float* Wv      = (const float*)d_in[8];
    const float* Wo      = (const float*)d_in[9];
    const float* ln1_g   = (const float*)d_in[10];
    const float* ln1_b   = (const float*)d_in[11];
    const float* Wg1     = (const float*)d_in[12];
    const float* bg1     = (const float*)d_in[13];
    const float* Wg2     = (const float*)d_in[14];
    const float* bg2     = (const float*)d_in[15];
    const float* norm_g  = (const float*)d_in[16];
    const float* norm_b  = (const float*)d_in[17];

    float* out = (float*)d_out;
    const size_t BLD = (size_t)BL * DD;
    float* f_fused = out;
    float* f_ap    = out + BLD;
    float* f_wm    = out + 2*BLD;
    float* f_mx    = out + 3*BLD;
    float* f_am    = out + 4*BLD;
    float* f_nsw   = out + 4*BLD + (size_t)BL*KK;

    char* base = (char*)d_ws;
    const size_t MD2 = (size_t)MM * DD * 2;     // 32 MB per fp16 activation buffer
    unsigned short* Xh = (unsigned short*)(base);
    unsigned short* Qh = (unsigned short*)(base + MD2);       // Q|K|V contiguous:
    unsigned short* Kh = (unsigned short*)(base + 2*MD2);     //  QKV routing relies
    unsigned short* Vh = (unsigned short*)(base + 3*MD2);     //  on this layout
    unsigned short* Wb = (unsigned short*)(base + 4*MD2);     // 4 MB weights
    float* rmask = (float*)(base + 4*MD2 + (size_t)WTOT*2);
    unsigned short* PVh  = Xh;   // pooled V-combination (BL,512) fp16
                                 //  (X dead after QKV; g1 overwrites later)
    unsigned short* Hin  = Vh;   // (B,L,1536) fp16 (V dead after attn)
    unsigned short* Hbuf = Xh;   // gelu(h) (B,L,512) fp16 (pooled dead after ap_gemm)
    float* preb = (float*)Kh;    // pre-LN fusion (BL,512) fp32 (K dead after attn)
    const unsigned short* Wqkv = Wb;            // (1536, 512) = [Wq;Wk;Wv]
    const unsigned short* Woh  = Wb + 3*WSZ;
    const unsigned short* Wg1h = Wb + OG1;
    const unsigned short* Wg2h = Wb + OG2;

    dim3 blk(256);

    cvt_weights<<<WTOT/1024, blk, 0, stream>>>(Wq, Wk, Wv, Wo, Wg1, Wg2, Wb);
    buildx_kernel<<<(BL*128)/256, blk, 0, stream>>>(SR, residue, pres, roles, role_emb,
                                                    sw, Xh, rmask, f_wm, f_mx, f_nsw);

    // Fused QKV: round-3 verified 256x128 pipelined LDS kernel.
    gemm_qkv_8p<<<dim3(1536), dim3(512), 0, stream>>>(Xh, Wqkv, Qh);

    // Attention + pooled PV (pool-before-Wo): writes PVh (BL,512) fp16.
    attn_kernel<<<BL, blk, 0, stream>>>(Qh, Kh, Vh, PVh, sw, pres, rmask, f_am);

    // f_ap = pooled @ Wo^T: 4x-smaller GEMM, pipelined 128x128, 256 blocks.
    ap_gemm<<<dim3(256), blk, 0, stream>>>(PVh, Woh, f_ap);

    // LN1 over [ap|wm|mx] -> hin fp16.
    ln1_kernel<<<dim3(BL/4), blk, 0, stream>>>(
        f_ap, f_wm, f_mx, ln1_g, ln1_b, Hin);

    // Wg1 + GELU: pipelined 128x128 kernel, 256 blocks.
    gemm_g1<<<dim3(256), blk, 0, stream>>>(Hin, Wg1h, Hbuf, bg1);

    // Wg2 + gate + fusion (pointwise): pipelined 128x128, 256 blocks.
    wg2_gemm<<<dim3(256), blk, 0, stream>>>(
        Hbuf, Wg2h, bg2, f_ap, f_wm, f_mx, preb);

    // Final LN -> fused.
    final_ln_kernel<<<dim3(BL/4), blk, 0, stream>>>(
        preb, norm_g, norm_b, f_fused);
}